// Round 1
// baseline (235.417 us; speedup 1.0000x reference)
//
#include <hip/hip_runtime.h>

// GlobalGatedUpdater, round 4: one (graph, chunk) per block — fill-shaped streaming.
//
// R3 post-mortem: the "graph-loop outer" restructure still issued per-thread
// store sequences cycling b=0..15 at 12.8 MB stride (16 interleaved write
// streams per wave) -> DRAM row thrash, ~2.4 TB/s vs the 6.6 TB/s the harness
// poison-fill achieves on the SAME output buffer. Root cause is the store
// instruction sequence, not which data sits in registers.
//
// R4: grid = (chunks, B). Each block owns ONE contiguous 20 KB slice of ONE
// graph's output: load emb slice (LLC-resident, 12.8 MB << 256 MB L3), patch
// touched rows via a per-block LDS last_j table built from that graph's 50
// node ids (atomicMax == last-write-wins), store contiguously. Store pattern
// is now identical to fillBufferAligned: one linear stream per block.

#define DIM 64
#define SEGS (DIM / 4)          // 16 float4 per row
#define BLOCK 256
#define KF 5                    // float4 per thread
#define TILE (BLOCK * KF)       // 1280 float4 = 20 KB per block
#define NROWS (TILE / SEGS)     // 80 rows per block-tile

__global__ __launch_bounds__(BLOCK) void ggu_stream(
    const int* __restrict__ nodes,        // (B*n)
    const float4* __restrict__ feat,      // (B*n, SEGS)
    const float4* __restrict__ emb,       // (items, SEGS)
    const float* __restrict__ alpha,      // (items)
    float4* __restrict__ out,             // (B, items, SEGS)
    int items, int n)
{
    const int b = blockIdx.y;
    const size_t rowsF4 = (size_t)items * SEGS;          // 800000 float4 / graph
    const size_t base   = (size_t)blockIdx.x * TILE;     // float4 offset in graph
    const int row0      = (int)(base / SEGS);            // first row of this tile

    // last_j[local_row] = last j in graph b touching that row, else -1
    __shared__ int lastj[NROWS];
    for (int i = threadIdx.x; i < NROWS; i += BLOCK) lastj[i] = -1;
    __syncthreads();
    for (int j = threadIdx.x; j < n; j += BLOCK) {
        const int local = nodes[b * n + j] - row0;
        if ((unsigned)local < (unsigned)NROWS)
            atomicMax(&lastj[local], j);                 // max j == last write wins
    }
    __syncthreads();

    const float4* e = emb + base;
    float4* o = out + (size_t)b * rowsF4 + base;

    #pragma unroll
    for (int k = 0; k < KF; ++k) {
        const int off = k * BLOCK + (int)threadIdx.x;    // 0..TILE-1
        if (base + (size_t)off < rowsF4) {
            float4 v = e[off];                           // LLC-resident re-read
            const int jl = lastj[off >> 4];              // one broadcast LDS read
            if (jl >= 0) {                               // rare: ~800/800000 rows
                const int row = row0 + (off >> 4);
                const float a = alpha[row];
                const float4 f = feat[(size_t)(b * n + jl) * SEGS + (off & (SEGS - 1))];
                const float om = 1.0f - a;
                v.x = om * v.x + a * f.x;
                v.y = om * v.y + a * f.y;
                v.z = om * v.z + a * f.z;
                v.w = om * v.w + a * f.w;
            }
            o[off] = v;                                  // contiguous stream store
        }
    }
}

extern "C" void kernel_launch(void* const* d_in, const int* in_sizes, int n_in,
                              void* d_out, int out_size, void* d_ws, size_t ws_size,
                              hipStream_t stream) {
    const int*   nodes = (const int*)d_in[0];
    const float* feat  = (const float*)d_in[1];
    const float* emb   = (const float*)d_in[2];
    const float* alpha = (const float*)d_in[3];

    const int items = in_sizes[3];                 // 50000 (alpha element count)
    const int B     = out_size / (items * DIM);    // 16
    const int n     = in_sizes[0] / B;             // 50

    const size_t rowsF4 = (size_t)items * SEGS;    // 800000
    const unsigned gx = (unsigned)((rowsF4 + TILE - 1) / TILE);  // 625
    dim3 grid(gx, (unsigned)B);                    // 10000 blocks, 20 KB each

    ggu_stream<<<grid, BLOCK, 0, stream>>>(
        nodes, (const float4*)feat, (const float4*)emb, alpha,
        (float4*)d_out, items, n);
}